// Round 1
// baseline (102.265 us; speedup 1.0000x reference)
//
#include <hip/hip_runtime.h>
#include <math.h>

#define NCOLS 4096

// ---------------------------------------------------------------------------
// prep: inv_var[n] = 1/softplus(sigma[n]); logdet = sum log(softplus(sigma));
// zero the quad accumulator. One block, trivial cost (~4096 elements).
// ---------------------------------------------------------------------------
__global__ void gauss_prep_kernel(const float* __restrict__ sigma,
                                  float* __restrict__ ws_scalars,
                                  float* __restrict__ inv_var) {
    __shared__ float red[256];
    const int t = threadIdx.x;
    float ld = 0.0f;
    for (int n = t; n < NCOLS; n += 256) {
        float x = sigma[n];
        // numerically stable softplus: max(x,0) + log1p(exp(-|x|))
        float sp = fmaxf(x, 0.0f) + log1pf(expf(-fabsf(x)));
        inv_var[n] = 1.0f / sp;
        ld += logf(sp);
    }
    red[t] = ld;
    __syncthreads();
    for (int s = 128; s > 0; s >>= 1) {
        if (t < s) red[t] += red[t + s];
        __syncthreads();
    }
    if (t == 0) {
        ws_scalars[0] = 0.0f;   // quad accumulator (atomicAdd target)
        ws_scalars[1] = red[0]; // logdet
    }
}

// ---------------------------------------------------------------------------
// main: each thread owns one float4 column (1024 threads x 4 = 4096 = N),
// loads inv_var once into registers, grid-strides over rows. Coalesced
// float4 loads of pred/gt. Block-reduce -> one atomicAdd per block.
// ---------------------------------------------------------------------------
__global__ __launch_bounds__(1024) void gauss_quad_kernel(
        const float* __restrict__ pred,
        const float* __restrict__ gt,
        const float* __restrict__ inv_var,
        float* __restrict__ ws_scalars,
        int B) {
    const int c4 = threadIdx.x;  // float4 column index, 0..1023
    const float4 iv = reinterpret_cast<const float4*>(inv_var)[c4];

    float acc = 0.0f;
    for (int r = blockIdx.x; r < B; r += gridDim.x) {
        const size_t base = (size_t)r * NCOLS + 4 * (size_t)c4;
        const float4 p = *reinterpret_cast<const float4*>(pred + base);
        const float4 g = *reinterpret_cast<const float4*>(gt + base);
        const float dx = g.x - p.x;
        const float dy = g.y - p.y;
        const float dz = g.z - p.z;
        const float dw = g.w - p.w;
        acc += dx * dx * iv.x + dy * dy * iv.y + dz * dz * iv.z + dw * dw * iv.w;
    }

    // wave (64-lane) shuffle reduction
    for (int off = 32; off > 0; off >>= 1)
        acc += __shfl_down(acc, off, 64);

    __shared__ float wred[16];
    const int wave = threadIdx.x >> 6;
    const int lane = threadIdx.x & 63;
    if (lane == 0) wred[wave] = acc;
    __syncthreads();
    if (wave == 0) {
        float v = (lane < 16) ? wred[lane] : 0.0f;
        for (int off = 8; off > 0; off >>= 1)
            v += __shfl_down(v, off, 64);
        if (lane == 0) atomicAdd(&ws_scalars[0], v);
    }
}

// ---------------------------------------------------------------------------
// finalize: out = 0.5 * (quad + B*(logdet + N*log(2*pi)))
// ---------------------------------------------------------------------------
__global__ void gauss_finalize_kernel(const float* __restrict__ ws_scalars,
                                      float* __restrict__ out, int B) {
    const double LOG_2PI = 1.8378770664093453;
    double quad = (double)ws_scalars[0];
    double logdet = (double)ws_scalars[1];
    out[0] = (float)(0.5 * (quad + (double)B * (logdet + (double)NCOLS * LOG_2PI)));
}

extern "C" void kernel_launch(void* const* d_in, const int* in_sizes, int n_in,
                              void* d_out, int out_size, void* d_ws, size_t ws_size,
                              hipStream_t stream) {
    const float* pred  = (const float*)d_in[0];
    const float* gt    = (const float*)d_in[1];
    const float* sigma = (const float*)d_in[2];
    float* out = (float*)d_out;

    float* scalars = (float*)d_ws;       // [0]=quad acc, [1]=logdet
    float* inv_var = (float*)d_ws + 4;   // 4096 floats, 16B-aligned

    const int B = in_sizes[0] / NCOLS;   // 8192

    gauss_prep_kernel<<<1, 256, 0, stream>>>(sigma, scalars, inv_var);
    gauss_quad_kernel<<<2048, 1024, 0, stream>>>(pred, gt, inv_var, scalars, B);
    gauss_finalize_kernel<<<1, 1, 0, stream>>>(scalars, out, B);
}

// Round 2
// 65.678 us; speedup vs baseline: 1.5571x; 1.5571x over previous
//
#include <hip/hip_runtime.h>
#include <math.h>

#define NCOLS 4096
#define NC4   1024                 // float4 columns per row
#define TPB   256
#define GRID  2048
#define NTHREADS (GRID * TPB)      // 524288 threads
#define RSTRIDE (NTHREADS / NC4)   // 512 rows covered per stride

// ---------------------------------------------------------------------------
// prep: inv_var[n] = 1/softplus(sigma[n]); logdet = sum log(softplus(sigma)).
// One block, ~4096 elements, trivial cost.
// ---------------------------------------------------------------------------
__global__ void gauss_prep_kernel(const float* __restrict__ sigma,
                                  float* __restrict__ ws_scalars,
                                  float* __restrict__ inv_var) {
    __shared__ float red[256];
    const int t = threadIdx.x;
    float ld = 0.0f;
    for (int n = t; n < NCOLS; n += 256) {
        float x = sigma[n];
        // numerically stable softplus: max(x,0) + log1p(exp(-|x|))
        float sp = fmaxf(x, 0.0f) + log1pf(expf(-fabsf(x)));
        inv_var[n] = 1.0f / sp;
        ld += logf(sp);
    }
    red[t] = ld;
    __syncthreads();
    for (int s = 128; s > 0; s >>= 1) {
        if (t < s) red[t] += red[t + s];
        __syncthreads();
    }
    if (t == 0) ws_scalars[0] = red[0];  // logdet
}

// ---------------------------------------------------------------------------
// quad: thread g owns float4-column (g & 1023); rows g>>10 + k*512.
// Hand-unrolled x4 -> 8 independent 16B loads in flight per step, 4 acc
// chains. Block reduce -> partials[blockIdx.x] (no atomics).
// ---------------------------------------------------------------------------
__global__ __launch_bounds__(TPB) void gauss_quad_kernel(
        const float4* __restrict__ pred,
        const float4* __restrict__ gt,
        const float* __restrict__ inv_var,
        float* __restrict__ partials,
        int B) {
    const int g  = blockIdx.x * TPB + threadIdx.x;
    const int c4 = g & (NC4 - 1);
    const int r0 = g >> 10;

    const float4 iv = reinterpret_cast<const float4*>(inv_var)[c4];

    float a0 = 0.0f, a1 = 0.0f, a2 = 0.0f, a3 = 0.0f;

    int r = r0;
    // main unrolled-by-4 row loop: 8 independent streaming loads per step
    for (; r + 3 * RSTRIDE < B; r += 4 * RSTRIDE) {
        const size_t i0 = (size_t)(r + 0 * RSTRIDE) * NC4 + c4;
        const size_t i1 = (size_t)(r + 1 * RSTRIDE) * NC4 + c4;
        const size_t i2 = (size_t)(r + 2 * RSTRIDE) * NC4 + c4;
        const size_t i3 = (size_t)(r + 3 * RSTRIDE) * NC4 + c4;
        const float4 p0 = pred[i0], g0 = gt[i0];
        const float4 p1 = pred[i1], g1 = gt[i1];
        const float4 p2 = pred[i2], g2 = gt[i2];
        const float4 p3 = pred[i3], g3 = gt[i3];

        float dx, dy, dz, dw;
        dx = g0.x - p0.x; dy = g0.y - p0.y; dz = g0.z - p0.z; dw = g0.w - p0.w;
        a0 += dx * dx * iv.x + dy * dy * iv.y + dz * dz * iv.z + dw * dw * iv.w;
        dx = g1.x - p1.x; dy = g1.y - p1.y; dz = g1.z - p1.z; dw = g1.w - p1.w;
        a1 += dx * dx * iv.x + dy * dy * iv.y + dz * dz * iv.z + dw * dw * iv.w;
        dx = g2.x - p2.x; dy = g2.y - p2.y; dz = g2.z - p2.z; dw = g2.w - p2.w;
        a2 += dx * dx * iv.x + dy * dy * iv.y + dz * dz * iv.z + dw * dw * iv.w;
        dx = g3.x - p3.x; dy = g3.y - p3.y; dz = g3.z - p3.z; dw = g3.w - p3.w;
        a3 += dx * dx * iv.x + dy * dy * iv.y + dz * dz * iv.z + dw * dw * iv.w;
    }
    // cleanup (not taken for B=8192, kept for generality)
    for (; r < B; r += RSTRIDE) {
        const size_t i = (size_t)r * NC4 + c4;
        const float4 p = pred[i], gg = gt[i];
        float dx = gg.x - p.x, dy = gg.y - p.y, dz = gg.z - p.z, dw = gg.w - p.w;
        a0 += dx * dx * iv.x + dy * dy * iv.y + dz * dz * iv.z + dw * dw * iv.w;
    }

    float acc = (a0 + a1) + (a2 + a3);

    // wave (64-lane) shuffle reduction
    for (int off = 32; off > 0; off >>= 1)
        acc += __shfl_down(acc, off, 64);

    __shared__ float wred[4];
    const int wave = threadIdx.x >> 6;
    const int lane = threadIdx.x & 63;
    if (lane == 0) wred[wave] = acc;
    __syncthreads();
    if (threadIdx.x == 0)
        partials[blockIdx.x] = (wred[0] + wred[1]) + (wred[2] + wred[3]);
}

// ---------------------------------------------------------------------------
// finalize: reduce 2048 block partials, combine with logdet, write scalar.
// ---------------------------------------------------------------------------
__global__ __launch_bounds__(1024) void gauss_finalize_kernel(
        const float* __restrict__ partials,
        const float* __restrict__ ws_scalars,
        float* __restrict__ out, int B) {
    const int t = threadIdx.x;
    float v = partials[t] + partials[t + 1024];

    for (int off = 32; off > 0; off >>= 1)
        v += __shfl_down(v, off, 64);

    __shared__ float wred[16];
    const int wave = t >> 6;
    const int lane = t & 63;
    if (lane == 0) wred[wave] = v;
    __syncthreads();
    if (t == 0) {
        float quad = 0.0f;
        for (int w = 0; w < 16; ++w) quad += wred[w];
        const double LOG_2PI = 1.8378770664093453;
        double logdet = (double)ws_scalars[0];
        out[0] = (float)(0.5 * ((double)quad +
                                 (double)B * (logdet + (double)NCOLS * LOG_2PI)));
    }
}

extern "C" void kernel_launch(void* const* d_in, const int* in_sizes, int n_in,
                              void* d_out, int out_size, void* d_ws, size_t ws_size,
                              hipStream_t stream) {
    const float* pred  = (const float*)d_in[0];
    const float* gt    = (const float*)d_in[1];
    const float* sigma = (const float*)d_in[2];
    float* out = (float*)d_out;

    float* scalars  = (float*)d_ws;              // [0]=logdet
    float* inv_var  = (float*)d_ws + 4;          // 4096 floats (16B aligned)
    float* partials = (float*)d_ws + 4 + NCOLS;  // 2048 floats

    const int B = in_sizes[0] / NCOLS;           // 8192

    gauss_prep_kernel<<<1, 256, 0, stream>>>(sigma, scalars, inv_var);
    gauss_quad_kernel<<<GRID, TPB, 0, stream>>>(
        (const float4*)pred, (const float4*)gt, inv_var, partials, B);
    gauss_finalize_kernel<<<1, 1024, 0, stream>>>(partials, scalars, out, B);
}

// Round 3
// 50.723 us; speedup vs baseline: 2.0161x; 1.2948x over previous
//
#include <hip/hip_runtime.h>
#include <math.h>

#define NCOLS 4096
#define NC4   1024                // float4 columns per row
#define TPB   1024                // one float4-row per block pass
#define ROWS_PER_BLOCK 16         // 512 blocks for B=8192 -> 2 blocks/CU

__device__ __forceinline__ float softplus_f(float x) {
    // numerically stable: max(x,0) + log1p(exp(-|x|))
    return fmaxf(x, 0.0f) + log1pf(expf(-fabsf(x)));
}

// ---------------------------------------------------------------------------
// quad: block b owns contiguous rows [b*16, b*16+16). Thread t owns float4
// column t (iv computed once from sigma). Unroll 4 rows -> 8 independent
// 16B loads in flight; the block's in-flight set is two contiguous 64 KB
// chunks (pred, gt) -> sequential DRAM/L3 streams.
// ---------------------------------------------------------------------------
__global__ __launch_bounds__(TPB, 8) void gauss_quad_kernel(
        const float4* __restrict__ pred,
        const float4* __restrict__ gt,
        const float* __restrict__ sigma,
        float* __restrict__ partials,
        int B) {
    const int c4 = threadIdx.x;                    // 0..1023
    const int r0 = blockIdx.x * ROWS_PER_BLOCK;

    // per-thread inv_var (once)
    const float4 s4 = reinterpret_cast<const float4*>(sigma)[c4];
    float4 iv;
    iv.x = 1.0f / softplus_f(s4.x);
    iv.y = 1.0f / softplus_f(s4.y);
    iv.z = 1.0f / softplus_f(s4.z);
    iv.w = 1.0f / softplus_f(s4.w);

    float a0 = 0.0f, a1 = 0.0f, a2 = 0.0f, a3 = 0.0f;

    const int rend = (r0 + ROWS_PER_BLOCK < B) ? ROWS_PER_BLOCK : (B - r0);
    int r = 0;
    for (; r + 3 < rend; r += 4) {
        const size_t i0 = (size_t)(r0 + r) * NC4 + c4;
        const float4 p0 = pred[i0 + 0 * NC4], g0 = gt[i0 + 0 * NC4];
        const float4 p1 = pred[i0 + 1 * NC4], g1 = gt[i0 + 1 * NC4];
        const float4 p2 = pred[i0 + 2 * NC4], g2 = gt[i0 + 2 * NC4];
        const float4 p3 = pred[i0 + 3 * NC4], g3 = gt[i0 + 3 * NC4];

        float dx, dy, dz, dw;
        dx = g0.x - p0.x; dy = g0.y - p0.y; dz = g0.z - p0.z; dw = g0.w - p0.w;
        a0 += dx * dx * iv.x + dy * dy * iv.y + dz * dz * iv.z + dw * dw * iv.w;
        dx = g1.x - p1.x; dy = g1.y - p1.y; dz = g1.z - p1.z; dw = g1.w - p1.w;
        a1 += dx * dx * iv.x + dy * dy * iv.y + dz * dz * iv.z + dw * dw * iv.w;
        dx = g2.x - p2.x; dy = g2.y - p2.y; dz = g2.z - p2.z; dw = g2.w - p2.w;
        a2 += dx * dx * iv.x + dy * dy * iv.y + dz * dz * iv.z + dw * dw * iv.w;
        dx = g3.x - p3.x; dy = g3.y - p3.y; dz = g3.z - p3.z; dw = g3.w - p3.w;
        a3 += dx * dx * iv.x + dy * dy * iv.y + dz * dz * iv.z + dw * dw * iv.w;
    }
    for (; r < rend; ++r) {  // generic tail (empty for B=8192)
        const size_t i = (size_t)(r0 + r) * NC4 + c4;
        const float4 p = pred[i], g = gt[i];
        float dx = g.x - p.x, dy = g.y - p.y, dz = g.z - p.z, dw = g.w - p.w;
        a0 += dx * dx * iv.x + dy * dy * iv.y + dz * dz * iv.z + dw * dw * iv.w;
    }

    float acc = (a0 + a1) + (a2 + a3);

    // wave (64-lane) shuffle reduction
    for (int off = 32; off > 0; off >>= 1)
        acc += __shfl_down(acc, off, 64);

    __shared__ float wred[16];
    const int wave = threadIdx.x >> 6;
    const int lane = threadIdx.x & 63;
    if (lane == 0) wred[wave] = acc;
    __syncthreads();
    if (threadIdx.x == 0) {
        float s = 0.0f;
        for (int w = 0; w < 16; ++w) s += wred[w];
        partials[blockIdx.x] = s;
    }
}

// ---------------------------------------------------------------------------
// finalize: one block. Reduce nblocks partials + logdet(sigma) inline.
// ---------------------------------------------------------------------------
__global__ __launch_bounds__(1024) void gauss_finalize_kernel(
        const float* __restrict__ partials,
        const float* __restrict__ sigma,
        float* __restrict__ out, int B, int nblocks) {
    const int t = threadIdx.x;

    float q = 0.0f;
    for (int i = t; i < nblocks; i += 1024) q += partials[i];

    float ld = 0.0f;
    for (int n = t; n < NCOLS; n += 1024) ld += logf(softplus_f(sigma[n]));

    for (int off = 32; off > 0; off >>= 1) {
        q  += __shfl_down(q, off, 64);
        ld += __shfl_down(ld, off, 64);
    }

    __shared__ float wq[16], wl[16];
    const int wave = t >> 6;
    const int lane = t & 63;
    if (lane == 0) { wq[wave] = q; wl[wave] = ld; }
    __syncthreads();
    if (t == 0) {
        float quad = 0.0f, logdet = 0.0f;
        for (int w = 0; w < 16; ++w) { quad += wq[w]; logdet += wl[w]; }
        const double LOG_2PI = 1.8378770664093453;
        out[0] = (float)(0.5 * ((double)quad +
                                 (double)B * ((double)logdet +
                                              (double)NCOLS * LOG_2PI)));
    }
}

extern "C" void kernel_launch(void* const* d_in, const int* in_sizes, int n_in,
                              void* d_out, int out_size, void* d_ws, size_t ws_size,
                              hipStream_t stream) {
    const float* pred  = (const float*)d_in[0];
    const float* gt    = (const float*)d_in[1];
    const float* sigma = (const float*)d_in[2];
    float* out = (float*)d_out;

    float* partials = (float*)d_ws;   // up to B/ROWS_PER_BLOCK floats

    const int B = in_sizes[0] / NCOLS;                     // 8192
    const int nblocks = (B + ROWS_PER_BLOCK - 1) / ROWS_PER_BLOCK;  // 512

    gauss_quad_kernel<<<nblocks, TPB, 0, stream>>>(
        (const float4*)pred, (const float4*)gt, sigma, partials, B);
    gauss_finalize_kernel<<<1, 1024, 0, stream>>>(partials, sigma, out, B, nblocks);
}